// Round 18
// baseline (219.393 us; speedup 1.0000x reference)
//
#include <hip/hip_runtime.h>
#include <hip/hip_bf16.h>

typedef __attribute__((ext_vector_type(8))) unsigned short ushort8;
typedef __attribute__((ext_vector_type(4))) float f32x4;
typedef __attribute__((ext_vector_type(8))) __bf16 bf16x8;
typedef unsigned int u32_g __attribute__((address_space(1)));
typedef unsigned int u32_l __attribute__((address_space(3)));

__device__ __forceinline__ float bf2f(unsigned short u) {
  union { unsigned u; float f; } v; v.u = ((unsigned)u) << 16; return v.f;
}
__device__ __forceinline__ unsigned short f2bf(float f) {
  union { float f; unsigned u; } v; v.f = f;
  unsigned r = v.u + 0x7FFFu + ((v.u >> 16) & 1u);
  return (unsigned short)(r >> 16);
}
__device__ __forceinline__ unsigned cvtpk_bf16(float lo, float hi) {
  unsigned r;
  asm("v_cvt_pk_bf16_f32 %0, %1, %2" : "=v"(r) : "v"(lo), "v"(hi));
  return r;
}
__device__ __forceinline__ f32x4 mfma16(bf16x8 a, bf16x8 b, f32x4 c) {
  return __builtin_amdgcn_mfma_f32_16x16x32_bf16(a, b, c, 0, 0, 0);
}
__device__ __forceinline__ void gload16(const void* g, void* l) {
  __builtin_amdgcn_global_load_lds((const u32_g*)g, (u32_l*)l, 16, 0, 0);
}

// ---------------- weight transpose+cast: W[K][N] fp32 -> WT[row_off+n][k] bf16
__global__ __launch_bounds__(256) void transpose_cast(
    const float* __restrict__ W, unsigned short* __restrict__ WT,
    int K, int N, int ldwt, int row_off)
{
  __shared__ unsigned short t[64 * 80];
  int n0 = blockIdx.x * 64, k0 = blockIdx.y * 64;
  int tid = threadIdx.x;
#pragma unroll
  for (int i = 0; i < 4; i++) {
    int c = tid + 256 * i;
    int r = c >> 4, q = c & 15;
    float4 v = *(const float4*)&W[(size_t)(k0 + r) * N + n0 + q * 4];
    t[(q * 4 + 0) * 80 + r] = f2bf(v.x);
    t[(q * 4 + 1) * 80 + r] = f2bf(v.y);
    t[(q * 4 + 2) * 80 + r] = f2bf(v.z);
    t[(q * 4 + 3) * 80 + r] = f2bf(v.w);
  }
  __syncthreads();
#pragma unroll
  for (int i = 0; i < 2; i++) {
    int c = tid + 256 * i;
    int n = c >> 3, p = c & 7;
    *(ushort8*)&WT[(size_t)(row_off + n0 + n) * ldwt + k0 + p * 8] =
        *(const ushort8*)&t[n * 80 + p * 8];
  }
}

__global__ void biascat_kernel(const float* __restrict__ bq, const float* __restrict__ bk,
                               const float* __restrict__ bv, const float* __restrict__ bg,
                               float* __restrict__ bcat)
{
  int i = blockIdx.x * 256 + threadIdx.x;   // 6144
  float v;
  if (i < 1024) v = bq[i];
  else if (i < 2048) v = bk[i - 1024];
  else if (i < 4096) v = bv[i - 2048];
  else v = bg[i - 4096];
  bcat[i] = v;
}

__global__ void cast_x_kernel(const float* __restrict__ x, unsigned short* __restrict__ xb)
{
  size_t i = (size_t)(blockIdx.x * 256 + threadIdx.x) * 4;
  float4 v = *(const float4*)&x[i];
  unsigned r0 = (unsigned)f2bf(v.x) | ((unsigned)f2bf(v.y) << 16);
  unsigned r1 = (unsigned)f2bf(v.z) | ((unsigned)f2bf(v.w) << 16);
  uint2 o; o.x = r0; o.y = r1;
  *(uint2*)&xb[i] = o;
}

// ---------------- GEMM3: 128xBN tile, BK=32, 3-buffer counted-vmcnt pipeline,
// 2D super-tile XCD mapping (R14; ~5MB concurrent working set per XCD).
template<int OUT_BF16, int BN, int SM, int SN>
__global__ __launch_bounds__(256, 3) void gemm3_kernel(
    const unsigned short* __restrict__ A, const unsigned short* __restrict__ BT,
    const float* __restrict__ bias, void* __restrict__ Cout,
    int M, int N, int K)
{
  constexpr int BUFS = (128 + BN) * 32;          // shorts per buffer (A then B)
  constexpr int ACH  = 512;                      // A chunks per stage (128r x 4)
  constexpr int LPS  = (128 + BN) / 64;          // 16B loads per thread per stage
  constexpr int STB  = SM * SN;                  // blocks per super-tile
  __shared__ __attribute__((aligned(16))) unsigned short lds[3 * BUFS];
  int tid = threadIdx.x, wave = tid >> 6, lane = tid & 63;
  int lr = lane & 15, lg = lane >> 4;
  int gx = gridDim.x;
  int lin = blockIdx.x + gx * blockIdx.y;
  int cpx = (gx * gridDim.y) >> 3;               // blocks per XCD (nwg%8==0)
  int xcd = lin & 7, s = lin >> 3;
  int spx = cpx / STB;                           // super-tiles per XCD
  int sup = xcd * spx + s / STB;                 // consecutive sups share stm (A)
  int nSupN = gx / SN;
  int stm = sup / nSupN, stn = sup % nSupN;
  int idx = s % STB;
  int m0 = (stm * SM + idx / SN) * 128;
  int n0 = (stn * SN + idx % SN) * BN;
  int wr = (wave >> 1) * 64, wc = (wave & 1) * (BN / 2);
  constexpr int NR = BN / 32;

  // per-thread staging sources (pre-swizzled), 4 chunks/row, slot j^((r>>1)&3)
  const unsigned short* gsrc[LPS];
#pragma unroll
  for (int i = 0; i < LPS; i++) {
    int c = tid + i * 256;
    if (c < ACH) {
      int r = c >> 2, j = c & 3;
      gsrc[i] = A + (size_t)(m0 + r) * K + ((j ^ ((r >> 1) & 3)) << 3);
    } else {
      int c2 = c - ACH, r = c2 >> 2, j = c2 & 3;
      gsrc[i] = BT + (size_t)(n0 + r) * K + ((j ^ ((r >> 1) & 3)) << 3);
    }
  }

  auto stage = [&](int buf, int kt) {
    char* lb = (char*)(lds + buf * BUFS);
#pragma unroll
    for (int i = 0; i < LPS; i++)
      gload16(gsrc[i] + kt * 32, lb + (tid + i * 256) * 16);
  };

  f32x4 acc[4][NR] = {};
  int nk = K >> 5;                               // BK = 32
  stage(0, 0);
  stage(1, 1);
  int cb = 0;                                    // it % 3
  for (int it = 0; it < nk; it++) {
    if (it + 1 < nk) {
      if constexpr (LPS == 4) asm volatile("s_waitcnt vmcnt(4)" ::: "memory");
      else                    asm volatile("s_waitcnt vmcnt(3)" ::: "memory");
    } else {
      asm volatile("s_waitcnt vmcnt(0)" ::: "memory");
    }
    __builtin_amdgcn_sched_barrier(0);
    __builtin_amdgcn_s_barrier();
    __builtin_amdgcn_sched_barrier(0);
    if (it + 2 < nk) {
      int sb = cb + 2; if (sb >= 3) sb -= 3;
      stage(sb, it + 2);
    }
    const unsigned short* as = lds + cb * BUFS;
    const unsigned short* bs = as + 128 * 32;
    int csw = (lg ^ ((lr >> 1) & 3)) << 3;       // read-side swizzled chunk
    bf16x8 af[4], bfr[NR];
#pragma unroll
    for (int m = 0; m < 4; m++)
      af[m] = *(const bf16x8*)&as[(wr + m * 16 + lr) * 32 + csw];
#pragma unroll
    for (int n = 0; n < NR; n++)
      bfr[n] = *(const bf16x8*)&bs[(wc + n * 16 + lr) * 32 + csw];
    __builtin_amdgcn_s_setprio(1);
#pragma unroll
    for (int m = 0; m < 4; m++)
#pragma unroll
      for (int n = 0; n < NR; n++)
        acc[m][n] = mfma16(af[m], bfr[n], acc[m][n]);
    __builtin_amdgcn_s_setprio(0);
    cb++; if (cb == 3) cb = 0;
  }

#pragma unroll
  for (int m = 0; m < 4; m++) {
#pragma unroll
    for (int n = 0; n < NR; n++) {
      int col = n0 + wc + n * 16 + lr;
      float bv = bias ? bias[col] : 0.f;
#pragma unroll
      for (int r = 0; r < 4; r++) {
        int row = m0 + wr + m * 16 + lg * 4 + r;
        float v = acc[m][n][r] + bv;
        if (OUT_BF16)
          ((unsigned short*)Cout)[(size_t)row * N + col] = f2bf(v);
        else
          ((float*)Cout)[(size_t)row * N + col] = v;
      }
    }
  }
}

// ---------------- prep: RoPE for q,k -> [BH][S][64] bf16
__global__ __launch_bounds__(256) void prep_qk_kernel(
    const unsigned short* __restrict__ Y,
    unsigned short* __restrict__ qr, unsigned short* __restrict__ kr)
{
  int t = blockIdx.x * 256 + threadIdx.x;  // [bs:4096][h:16][j:32]
  int j = t & 31;
  int h = (t >> 5) & 15;
  int bs = t >> 9;
  int s = bs & 2047;
  int b = bs >> 11;
  float ang = __expf(-0.29710774f * (float)j);   // 10000^(-j/31)
  float th = (float)s * ang;
  float sn, cs;
  __sincosf(th, &sn, &cs);
  const unsigned short* yq = &Y[(size_t)bs * 6144 + h * 64 + 2 * j];
  unsigned qv = *(const unsigned*)yq;
  unsigned kv = *(const unsigned*)(yq + 1024);
  float q0 = bf2f((unsigned short)(qv & 0xffff));
  float q1 = bf2f((unsigned short)(qv >> 16));
  float k0 = bf2f((unsigned short)(kv & 0xffff)) * 0.125f;
  float k1 = bf2f((unsigned short)(kv >> 16)) * 0.125f;
  float qr0 = q0 * cs - q1 * sn, qr1 = q1 * cs + q0 * sn;
  float kr0 = k0 * cs - k1 * sn, kr1 = k1 * cs + k0 * sn;
  size_t o = ((size_t)(b * 16 + h) * 2048 + s) * 64 + 2 * j;
  *(unsigned*)&qr[o] = (unsigned)f2bf(qr0) | ((unsigned)f2bf(qr1) << 16);
  *(unsigned*)&kr[o] = (unsigned)f2bf(kr0) | ((unsigned)f2bf(kr1) << 16);
}

// ---------------- prep: v transpose -> vT[BH][128][2048] bf16
__global__ __launch_bounds__(256) void prep_v_kernel(
    const unsigned short* __restrict__ Y, unsigned short* __restrict__ vT)
{
  __shared__ unsigned short t[128 * 80];
  int s0 = blockIdx.x * 64;
  int bh = blockIdx.y;
  int b = bh >> 4, h = bh & 15;
  int tid = threadIdx.x;
#pragma unroll
  for (int i = 0; i < 4; i++) {
    int c = tid + 256 * i;
    int r = c >> 4, p = c & 15;
    ushort8 v = *(const ushort8*)&Y[(size_t)(b * 2048 + s0 + r) * 6144 + 2048 + h * 128 + p * 8];
#pragma unroll
    for (int e = 0; e < 8; e++) t[(p * 8 + e) * 80 + r] = v[e];
  }
  __syncthreads();
#pragma unroll
  for (int i = 0; i < 4; i++) {
    int c = tid + 256 * i;
    int d = c >> 3, p = c & 7;
    *(ushort8*)&vT[((size_t)bh * 128 + d) * 2048 + s0 + p * 8] = *(const ushort8*)&t[d * 80 + p * 8];
  }
}

// ---------------- retention: swapped-QK, XCD-local bh, DMA double-buffered K/V.
// One 64-row stile per block (1024 blocks, heavy-first per XCD); kk-split P
// region (16x40/wave, 5KB) -> LDS 54272B -> 3 blocks/CU co-resident.
#define PPAD 40
__global__ __launch_bounds__(256, 3) void retention_kernel(
    const unsigned short* __restrict__ qr, const unsigned short* __restrict__ kr,
    const unsigned short* __restrict__ vT, const unsigned short* __restrict__ Yg,
    unsigned short* __restrict__ Z)
{
  // shorts: kA[4096] kB[4096] vA[8192] vB[8192] lp[4*16*40]
  __shared__ __attribute__((aligned(16))) unsigned short lds[24576 + 4 * 16 * PPAD];
  unsigned short* const lk0 = lds;
  unsigned short* const lk1 = lds + 4096;
  unsigned short* const lv0 = lds + 8192;
  unsigned short* const lv1 = lds + 16384;
  unsigned short* const lp  = lds + 24576;

  // XCD-locality: all 32 stiles of a bh on one XCD, heavy stiles first
  int lin = blockIdx.x;                     // 0..1023
  int xcd = lin & 7, s = lin >> 3;          // slot 0..127
  int bh = xcd + 8 * (s >> 5);              // 4 bh per XCD
  int stile = 31 - (s & 31);                // heavy first
  int b = bh >> 4, h = bh & 15;
  float decay = __logf(1.f - exp2f(-5.f - (float)h));
  int tid = threadIdx.x, wave = tid >> 6, lane = tid & 63;
  int lr = lane & 15, lg = lane >> 4;
  const unsigned short* qbase = &qr[(size_t)bh * 2048 * 64];
  const unsigned short* kbase = &kr[(size_t)bh * 2048 * 64];
  const unsigned short* vbase = &vT[(size_t)bh * 128 * 2048];
  unsigned short* lpw = &lp[wave * 16 * PPAD];
  int swz = (lr & 7) << 3;                  // read-side XOR swizzle (shorts)

  float cf[4][4];
#pragma unroll
  for (int nb = 0; nb < 4; nb++)
#pragma unroll
    for (int r = 0; r < 4; r++)
      cf[nb][r] = __expf(-decay * (float)(nb * 16 + lg * 4 + r));

  auto stage = [&](int bufi, int t0) {
    const char* kg = (const char*)(kbase + (size_t)t0 * 64);   // contiguous 8KB
    const char* vg = (const char*)vbase + (size_t)t0 * 2;
    char* lk = (char*)(bufi ? lk1 : lk0);
    char* lv = (char*)(bufi ? lv1 : lv0);
#pragma unroll
    for (int i = 0; i < 2; i++) {
      int c = tid + i * 256;                 // 512 chunks of 16B
      int r = c >> 3, j = c & 7;
      gload16(kg + r * 128 + ((j ^ (r & 7)) << 4), lk + c * 16);
    }
#pragma unroll
    for (int i = 0; i < 4; i++) {
      int c = tid + i * 256;                 // 1024 chunks of 16B
      int d = c >> 3, j = c & 7;
      gload16(vg + (size_t)d * 4096 + ((j ^ (d & 7)) << 4), lv + c * 16);
    }
  };

  int s0 = stile * 64;
  int sq = s0 + wave * 16 + lr;              // this lane's q-row
  bf16x8 qf0 = *(const bf16x8*)&qbase[(size_t)sq * 64 + lg * 8];
  bf16x8 qf1 = *(const bf16x8*)&qbase[(size_t)sq * 64 + 32 + lg * 8];
  f32x4 accv[8] = {};
  float rs = 0.f;
  int nt = stile + 1;

  stage(0, 0);
  __syncthreads();
  for (int it = 0; it < nt; it++) {
    int t0 = it * 64;
    if (it + 1 < nt) stage((it + 1) & 1, t0 + 64);   // overlap with compute
    const unsigned short* lk = (it & 1) ? lk1 : lk0;
    const unsigned short* lv = (it & 1) ? lv1 : lv0;
    bool bnd = (it == nt - 1);
    float rowf = __expf(decay * (float)(sq - t0));
#pragma unroll
    for (int half = 0; half < 2; half++) {
#pragma unroll
      for (int nl = 0; nl < 2; nl++) {
        int nb = half * 2 + nl;
        f32x4 sa = {};
        bf16x8 a0 = *(const bf16x8*)&lk[((nb * 16 + lr) * 64 + lg * 8) ^ swz];
        bf16x8 a1 = *(const bf16x8*)&lk[((nb * 16 + lr) * 64 + 32 + lg * 8) ^ swz];
        __builtin_amdgcn_s_setprio(1);
        sa = mfma16(a0, qf0, sa);            // S^T[t][q]
        sa = mfma16(a1, qf1, sa);
        __builtin_amdgcn_s_setprio(0);
        float pv[4];
#pragma unroll
        for (int r = 0; r < 4; r++) {
          float w = rowf * cf[nb][r];
          if (bnd) {
            int tt = t0 + nb * 16 + lg * 4 + r;
            w = (tt <= sq) ? w : 0.f;
          }
          pv[r] = sa[r] * w;
          rs += pv[r];
        }
        uint2 wv;
        wv.x = cvtpk_bf16(pv[0], pv[1]);
        wv.y = cvtpk_bf16(pv[2], pv[3]);
        *(uint2*)&lpw[lr * PPAD + nl * 16 + lg * 4] = wv;   // P[q][t_loc]
      }
      // PV for this half: t = half*32 + lg*8 + e (same-wave P read, no barrier)
      bf16x8 pa = *(const bf16x8*)&lpw[lr * PPAD + lg * 8];
      __builtin_amdgcn_s_setprio(1);
#pragma unroll
      for (int nb = 0; nb < 8; nb++) {
        bf16x8 bv = *(const bf16x8*)&lv[((nb * 16 + lr) * 64 + half * 32 + lg * 8) ^ swz];
        accv[nb] = mfma16(pa, bv, accv[nb]);
      }
      __builtin_amdgcn_s_setprio(0);
    }
    __syncthreads();                         // drains next-tile DMA + frees bufs
  }

  // epilogue: rowsum reduce over lg groups (q-row = lr within wave)
  rs += __shfl_xor(rs, 16);
  rs += __shfl_xor(rs, 32);
  int srb = s0 + wave * 16 + lg * 4;
  const unsigned short* gb2 = &Yg[((size_t)(b * 2048 + srb)) * 6144 + 4096 + h * 128];
  unsigned short* zb = &Z[((size_t)(b * 2048 + srb)) * 2048 + h * 128];
#pragma unroll
  for (int r = 0; r < 4; r++) {
    float rsq = __shfl(rs, lg * 4 + r);
    float sidx = (float)(srb + r);
    float geo = (1.f - __expf(decay * (sidx + 1.f))) * exp2f(5.f + (float)h);
    float invs = rsqrtf(geo);
    float den = fmaxf(fabsf(rsq * invs), 1.f);
    float scl = invs / den;
    float sm = 0.f, sq2 = 0.f;
#pragma unroll
    for (int nb = 0; nb < 8; nb++) {
      float v = accv[nb][r] * scl;
      sm += v; sq2 += v * v;
    }
    sm += __shfl_xor(sm, 1); sm += __shfl_xor(sm, 2);
    sm += __shfl_xor(sm, 4); sm += __shfl_xor(sm, 8);
    sq2 += __shfl_xor(sq2, 1); sq2 += __shfl_xor(sq2, 2);
    sq2 += __shfl_xor(sq2, 4); sq2 += __shfl_xor(sq2, 8);
    float mu = sm * (1.f / 128.f);
    float var = sq2 * (1.f / 128.f) - mu * mu;
    float istd = rsqrtf(var + 1e-5f);
#pragma unroll
    for (int nb = 0; nb < 8; nb++) {
      float v = accv[nb][r] * scl;
      float nrm = (v - mu) * istd;
      float g = bf2f(gb2[(size_t)r * 6144 + nb * 16 + lr]);
      float sg = g / (1.f + __expf(-g));
      zb[(size_t)r * 2048 + nb * 16 + lr] = f2bf(nrm * sg);
    }
  }
}

extern "C" void kernel_launch(void* const* d_in, const int* in_sizes, int n_in,
                              void* d_out, int out_size, void* d_ws, size_t ws_size,
                              hipStream_t stream) {
  const float* x  = (const float*)d_in[0];
  const float* Wq = (const float*)d_in[1];
  const float* bq = (const float*)d_in[2];
  const float* Wk = (const float*)d_in[3];
  const float* bk = (const float*)d_in[4];
  const float* Wv = (const float*)d_in[5];
  const float* bv = (const float*)d_in[6];
  const float* Wg = (const float*)d_in[7];
  const float* bg = (const float*)d_in[8];
  const float* Wo = (const float*)d_in[9];
  const float* bo = (const float*)d_in[10];

  char* ws = (char*)d_ws;
  unsigned short* xbf   = (unsigned short*)(ws);                 // [4096][1024]    8.4 MB
  unsigned short* wcatT = (unsigned short*)(ws + 8388608);       // [6144][1024]   12.6 MB
  unsigned short* woT   = (unsigned short*)(ws + 20971520);      // [1024][2048]    4.2 MB
  unsigned short* Y     = (unsigned short*)(ws + 25165824);      // [4096][6144]   50.3 MB
  unsigned short* qrb   = (unsigned short*)(ws + 75497472);      // [32][2048][64]  8.4 MB
  unsigned short* krb   = (unsigned short*)(ws + 83886080);      // [32][2048][64]  8.4 MB
  unsigned short* vT    = (unsigned short*)(ws + 92274688);      // [32][128][2048] 16.8 MB
  float*          bcat  = (float*)(ws + 109051904);              // [6144]
  unsigned short* Z     = xbf;   // aliases xbf+wcatT (16.8 MB), both dead after GEMM1

  // weights -> transposed bf16
  transpose_cast<<<dim3(16, 16), 256, 0, stream>>>(Wq, wcatT, 1024, 1024, 1024, 0);
  transpose_cast<<<dim3(16, 16), 256, 0, stream>>>(Wk, wcatT, 1024, 1024, 1024, 1024);
  transpose_cast<<<dim3(32, 16), 256, 0, stream>>>(Wv, wcatT, 1024, 2048, 1024, 2048);
  transpose_cast<<<dim3(32, 16), 256, 0, stream>>>(Wg, wcatT, 1024, 2048, 1024, 4096);
  transpose_cast<<<dim3(16, 32), 256, 0, stream>>>(Wo, woT, 2048, 1024, 2048, 0);
  biascat_kernel<<<24, 256, 0, stream>>>(bq, bk, bv, bg, bcat);
  cast_x_kernel<<<4096, 256, 0, stream>>>(x, xbf);

  // fused QKVG projection: Y = x @ [Wq|Wk|Wv|Wg] + bias (bf16 out)
  gemm3_kernel<1, 128, 8, 6><<<dim3(48, 32), 256, 0, stream>>>(xbf, wcatT, bcat, Y, 4096, 6144, 1024);

  // prep: RoPE(q,k), v-transpose
  prep_qk_kernel<<<8192, 256, 0, stream>>>(Y, qrb, krb);
  prep_v_kernel<<<dim3(32, 32), 256, 0, stream>>>(Y, vT);

  // retention + LN + silu gate -> Z (bf16); g read directly from Y
  retention_kernel<<<1024, 256, 0, stream>>>(qrb, krb, vT, Y, Z);

  // output projection: out = Z @ Wo + bo (fp32 out), super-tile 4m x 4n
  gemm3_kernel<0, 64, 4, 4><<<dim3(16, 32), 256, 0, stream>>>(Z, woT, bo, d_out, 4096, 1024, 2048);
}

// Round 19
// 183.324 us; speedup vs baseline: 1.1968x; 1.1968x over previous
//
#include <hip/hip_runtime.h>
#include <hip/hip_bf16.h>

typedef __attribute__((ext_vector_type(8))) unsigned short ushort8;
typedef __attribute__((ext_vector_type(4))) float f32x4;
typedef __attribute__((ext_vector_type(8))) __bf16 bf16x8;
typedef unsigned int u32_g __attribute__((address_space(1)));
typedef unsigned int u32_l __attribute__((address_space(3)));

__device__ __forceinline__ float bf2f(unsigned short u) {
  union { unsigned u; float f; } v; v.u = ((unsigned)u) << 16; return v.f;
}
__device__ __forceinline__ unsigned short f2bf(float f) {
  union { float f; unsigned u; } v; v.f = f;
  unsigned r = v.u + 0x7FFFu + ((v.u >> 16) & 1u);
  return (unsigned short)(r >> 16);
}
__device__ __forceinline__ unsigned cvtpk_bf16(float lo, float hi) {
  unsigned r;
  asm("v_cvt_pk_bf16_f32 %0, %1, %2" : "=v"(r) : "v"(lo), "v"(hi));
  return r;
}
__device__ __forceinline__ f32x4 mfma16(bf16x8 a, bf16x8 b, f32x4 c) {
  return __builtin_amdgcn_mfma_f32_16x16x32_bf16(a, b, c, 0, 0, 0);
}
__device__ __forceinline__ void gload16(const void* g, void* l) {
  __builtin_amdgcn_global_load_lds((const u32_g*)g, (u32_l*)l, 16, 0, 0);
}

// ---------------- mega prep: 5 weight transposes + cast_x + biascat in one launch
// blocks 0..2047: transpose_cast tiles; 2048..6143: cast_x; 6144..6167: biascat
__device__ __forceinline__ void tc_body(
    const float* __restrict__ W, unsigned short* __restrict__ WT,
    int K, int N, int ldwt, int row_off, int bx, int by, int tid,
    unsigned short* t)
{
  int n0 = bx * 64, k0 = by * 64;
#pragma unroll
  for (int i = 0; i < 4; i++) {
    int c = tid + 256 * i;
    int r = c >> 4, q = c & 15;
    float4 v = *(const float4*)&W[(size_t)(k0 + r) * N + n0 + q * 4];
    t[(q * 4 + 0) * 80 + r] = f2bf(v.x);
    t[(q * 4 + 1) * 80 + r] = f2bf(v.y);
    t[(q * 4 + 2) * 80 + r] = f2bf(v.z);
    t[(q * 4 + 3) * 80 + r] = f2bf(v.w);
  }
  __syncthreads();
#pragma unroll
  for (int i = 0; i < 2; i++) {
    int c = tid + 256 * i;
    int n = c >> 3, p = c & 7;
    *(ushort8*)&WT[(size_t)(row_off + n0 + n) * ldwt + k0 + p * 8] =
        *(const ushort8*)&t[n * 80 + p * 8];
  }
}

__global__ __launch_bounds__(256) void mega_prep_kernel(
    const float* __restrict__ x,
    const float* __restrict__ Wq, const float* __restrict__ Wk,
    const float* __restrict__ Wv, const float* __restrict__ Wg,
    const float* __restrict__ Wo,
    const float* __restrict__ bq, const float* __restrict__ bk,
    const float* __restrict__ bv, const float* __restrict__ bg,
    unsigned short* __restrict__ wcatT, unsigned short* __restrict__ woT,
    unsigned short* __restrict__ xbf, float* __restrict__ bcat)
{
  __shared__ unsigned short t[64 * 80];
  int bid = blockIdx.x, tid = threadIdx.x;
  if (bid < 256) {
    tc_body(Wq, wcatT, 1024, 1024, 1024, 0, bid & 15, bid >> 4, tid, t);
  } else if (bid < 512) {
    int l = bid - 256;
    tc_body(Wk, wcatT, 1024, 1024, 1024, 1024, l & 15, l >> 4, tid, t);
  } else if (bid < 1024) {
    int l = bid - 512;
    tc_body(Wv, wcatT, 1024, 2048, 1024, 2048, l & 31, l >> 5, tid, t);
  } else if (bid < 1536) {
    int l = bid - 1024;
    tc_body(Wg, wcatT, 1024, 2048, 1024, 4096, l & 31, l >> 5, tid, t);
  } else if (bid < 2048) {
    int l = bid - 1536;
    tc_body(Wo, woT, 2048, 1024, 2048, 0, l & 15, l >> 4, tid, t);
  } else if (bid < 6144) {
    size_t i = (size_t)((bid - 2048) * 256 + tid) * 4;
    float4 v = *(const float4*)&x[i];
    unsigned r0 = (unsigned)f2bf(v.x) | ((unsigned)f2bf(v.y) << 16);
    unsigned r1 = (unsigned)f2bf(v.z) | ((unsigned)f2bf(v.w) << 16);
    uint2 o; o.x = r0; o.y = r1;
    *(uint2*)&xbf[i] = o;
  } else {
    int i = (bid - 6144) * 256 + tid;   // 6144
    float v;
    if (i < 1024) v = bq[i];
    else if (i < 2048) v = bk[i - 1024];
    else if (i < 4096) v = bv[i - 2048];
    else v = bg[i - 4096];
    bcat[i] = v;
  }
}

// ---------------- GEMM3: 128xBN tile, BK=32, 3-buffer counted-vmcnt pipeline,
// 2D super-tile XCD mapping (R14; ~5MB concurrent working set per XCD).
template<int OUT_BF16, int BN, int SM, int SN>
__global__ __launch_bounds__(256, 3) void gemm3_kernel(
    const unsigned short* __restrict__ A, const unsigned short* __restrict__ BT,
    const float* __restrict__ bias, void* __restrict__ Cout,
    int M, int N, int K)
{
  constexpr int BUFS = (128 + BN) * 32;          // shorts per buffer (A then B)
  constexpr int ACH  = 512;                      // A chunks per stage (128r x 4)
  constexpr int LPS  = (128 + BN) / 64;          // 16B loads per thread per stage
  constexpr int STB  = SM * SN;                  // blocks per super-tile
  __shared__ __attribute__((aligned(16))) unsigned short lds[3 * BUFS];
  int tid = threadIdx.x, wave = tid >> 6, lane = tid & 63;
  int lr = lane & 15, lg = lane >> 4;
  int gx = gridDim.x;
  int lin = blockIdx.x + gx * blockIdx.y;
  int cpx = (gx * gridDim.y) >> 3;               // blocks per XCD (nwg%8==0)
  int xcd = lin & 7, s = lin >> 3;
  int spx = cpx / STB;                           // super-tiles per XCD
  int sup = xcd * spx + s / STB;                 // consecutive sups share stm (A)
  int nSupN = gx / SN;
  int stm = sup / nSupN, stn = sup % nSupN;
  int idx = s % STB;
  int m0 = (stm * SM + idx / SN) * 128;
  int n0 = (stn * SN + idx % SN) * BN;
  int wr = (wave >> 1) * 64, wc = (wave & 1) * (BN / 2);
  constexpr int NR = BN / 32;

  // per-thread staging sources (pre-swizzled), 4 chunks/row, slot j^((r>>1)&3)
  const unsigned short* gsrc[LPS];
#pragma unroll
  for (int i = 0; i < LPS; i++) {
    int c = tid + i * 256;
    if (c < ACH) {
      int r = c >> 2, j = c & 3;
      gsrc[i] = A + (size_t)(m0 + r) * K + ((j ^ ((r >> 1) & 3)) << 3);
    } else {
      int c2 = c - ACH, r = c2 >> 2, j = c2 & 3;
      gsrc[i] = BT + (size_t)(n0 + r) * K + ((j ^ ((r >> 1) & 3)) << 3);
    }
  }

  auto stage = [&](int buf, int kt) {
    char* lb = (char*)(lds + buf * BUFS);
#pragma unroll
    for (int i = 0; i < LPS; i++)
      gload16(gsrc[i] + kt * 32, lb + (tid + i * 256) * 16);
  };

  f32x4 acc[4][NR] = {};
  int nk = K >> 5;                               // BK = 32
  stage(0, 0);
  stage(1, 1);
  int cb = 0;                                    // it % 3
  for (int it = 0; it < nk; it++) {
    if (it + 1 < nk) {
      if constexpr (LPS == 4) asm volatile("s_waitcnt vmcnt(4)" ::: "memory");
      else                    asm volatile("s_waitcnt vmcnt(3)" ::: "memory");
    } else {
      asm volatile("s_waitcnt vmcnt(0)" ::: "memory");
    }
    __builtin_amdgcn_sched_barrier(0);
    __builtin_amdgcn_s_barrier();
    __builtin_amdgcn_sched_barrier(0);
    if (it + 2 < nk) {
      int sb = cb + 2; if (sb >= 3) sb -= 3;
      stage(sb, it + 2);
    }
    const unsigned short* as = lds + cb * BUFS;
    const unsigned short* bs = as + 128 * 32;
    int csw = (lg ^ ((lr >> 1) & 3)) << 3;       // read-side swizzled chunk
    bf16x8 af[4], bfr[NR];
#pragma unroll
    for (int m = 0; m < 4; m++)
      af[m] = *(const bf16x8*)&as[(wr + m * 16 + lr) * 32 + csw];
#pragma unroll
    for (int n = 0; n < NR; n++)
      bfr[n] = *(const bf16x8*)&bs[(wc + n * 16 + lr) * 32 + csw];
    __builtin_amdgcn_s_setprio(1);
#pragma unroll
    for (int m = 0; m < 4; m++)
#pragma unroll
      for (int n = 0; n < NR; n++)
        acc[m][n] = mfma16(af[m], bfr[n], acc[m][n]);
    __builtin_amdgcn_s_setprio(0);
    cb++; if (cb == 3) cb = 0;
  }

#pragma unroll
  for (int m = 0; m < 4; m++) {
#pragma unroll
    for (int n = 0; n < NR; n++) {
      int col = n0 + wc + n * 16 + lr;
      float bv = bias ? bias[col] : 0.f;
#pragma unroll
      for (int r = 0; r < 4; r++) {
        int row = m0 + wr + m * 16 + lg * 4 + r;
        float v = acc[m][n][r] + bv;
        if (OUT_BF16)
          ((unsigned short*)Cout)[(size_t)row * N + col] = f2bf(v);
        else
          ((float*)Cout)[(size_t)row * N + col] = v;
      }
    }
  }
}

// ---------------- prep2: RoPE(q,k) + v-transpose in one launch
// blocks 0..8191: qk; 8192..9215: v-transpose
__global__ __launch_bounds__(256) void prep2_kernel(
    const unsigned short* __restrict__ Y,
    unsigned short* __restrict__ qr, unsigned short* __restrict__ kr,
    unsigned short* __restrict__ vT)
{
  int bid = blockIdx.x, tid = threadIdx.x;
  if (bid < 8192) {
    int t = bid * 256 + tid;  // [bs:4096][h:16][j:32]
    int j = t & 31;
    int h = (t >> 5) & 15;
    int bs = t >> 9;
    int s = bs & 2047;
    int b = bs >> 11;
    float ang = __expf(-0.29710774f * (float)j);   // 10000^(-j/31)
    float th = (float)s * ang;
    float sn, cs;
    __sincosf(th, &sn, &cs);
    const unsigned short* yq = &Y[(size_t)bs * 6144 + h * 64 + 2 * j];
    unsigned qv = *(const unsigned*)yq;
    unsigned kv = *(const unsigned*)(yq + 1024);
    float q0 = bf2f((unsigned short)(qv & 0xffff));
    float q1 = bf2f((unsigned short)(qv >> 16));
    float k0 = bf2f((unsigned short)(kv & 0xffff)) * 0.125f;
    float k1 = bf2f((unsigned short)(kv >> 16)) * 0.125f;
    float qr0 = q0 * cs - q1 * sn, qr1 = q1 * cs + q0 * sn;
    float kr0 = k0 * cs - k1 * sn, kr1 = k1 * cs + k0 * sn;
    size_t o = ((size_t)(b * 16 + h) * 2048 + s) * 64 + 2 * j;
    *(unsigned*)&qr[o] = (unsigned)f2bf(qr0) | ((unsigned)f2bf(qr1) << 16);
    *(unsigned*)&kr[o] = (unsigned)f2bf(kr0) | ((unsigned)f2bf(kr1) << 16);
  } else {
    __shared__ unsigned short t[128 * 80];
    int l = bid - 8192;
    int s0 = (l & 31) * 64;
    int bh = l >> 5;
    int b = bh >> 4, h = bh & 15;
#pragma unroll
    for (int i = 0; i < 4; i++) {
      int c = tid + 256 * i;
      int r = c >> 4, p = c & 15;
      ushort8 v = *(const ushort8*)&Y[(size_t)(b * 2048 + s0 + r) * 6144 + 2048 + h * 128 + p * 8];
#pragma unroll
      for (int e = 0; e < 8; e++) t[(p * 8 + e) * 80 + r] = v[e];
    }
    __syncthreads();
#pragma unroll
    for (int i = 0; i < 4; i++) {
      int c = tid + 256 * i;
      int d = c >> 3, p = c & 7;
      *(ushort8*)&vT[((size_t)bh * 128 + d) * 2048 + s0 + p * 8] = *(const ushort8*)&t[d * 80 + p * 8];
    }
  }
}

// ---------------- retention: swapped-QK, XCD-local bh, DMA double-buffered K/V
// (R3 balanced-pair structure; P packing via v_cvt_pk_bf16_f32; T5 setprio)
#define LPAD 72
__global__ __launch_bounds__(256, 2) void retention_kernel(
    const unsigned short* __restrict__ qr, const unsigned short* __restrict__ kr,
    const unsigned short* __restrict__ vT, const unsigned short* __restrict__ Yg,
    unsigned short* __restrict__ Z)
{
  // shorts: kA[4096] kB[4096] vA[8192] vB[8192] lp[4*16*72]
  __shared__ __attribute__((aligned(16))) unsigned short lds[24576 + 4 * 16 * LPAD];
  unsigned short* const lk0 = lds;
  unsigned short* const lk1 = lds + 4096;
  unsigned short* const lv0 = lds + 8192;
  unsigned short* const lv1 = lds + 16384;
  unsigned short* const lp  = lds + 24576;

  // XCD-locality mapping: all 16 blocks of a bh on one XCD (wgid%8 round-robin)
  int lin = blockIdx.x;            // 0..511
  int xcd = lin & 7, slot = lin >> 3;       // slot 0..63
  int bh = xcd + 8 * (slot >> 4);           // 4 bh per XCD
  int bx = slot & 15;                       // pair index
  int b = bh >> 4, h = bh & 15;
  float decay = __logf(1.f - exp2f(-5.f - (float)h));
  int tid = threadIdx.x, wave = tid >> 6, lane = tid & 63;
  int lr = lane & 15, lg = lane >> 4;
  const unsigned short* qbase = &qr[(size_t)bh * 2048 * 64];
  const unsigned short* kbase = &kr[(size_t)bh * 2048 * 64];
  const unsigned short* vbase = &vT[(size_t)bh * 128 * 2048];
  unsigned short* lpw = &lp[wave * 16 * LPAD];
  int swz = (lr & 7) << 3;                  // read-side XOR swizzle (shorts)

  float cf[4][4];
#pragma unroll
  for (int nb = 0; nb < 4; nb++)
#pragma unroll
    for (int r = 0; r < 4; r++)
      cf[nb][r] = __expf(-decay * (float)(nb * 16 + lg * 4 + r));

  auto stage = [&](int bufi, int t0) {
    const char* kg = (const char*)(kbase + (size_t)t0 * 64);   // contiguous 8KB
    const char* vg = (const char*)vbase + (size_t)t0 * 2;
    char* lk = (char*)(bufi ? lk1 : lk0);
    char* lv = (char*)(bufi ? lv1 : lv0);
#pragma unroll
    for (int i = 0; i < 2; i++) {
      int c = tid + i * 256;                 // 512 chunks of 16B
      int r = c >> 3, j = c & 7;
      gload16(kg + r * 128 + ((j ^ (r & 7)) << 4), lk + c * 16);
    }
#pragma unroll
    for (int i = 0; i < 4; i++) {
      int c = tid + i * 256;                 // 1024 chunks of 16B
      int d = c >> 3, j = c & 7;
      gload16(vg + (size_t)d * 4096 + ((j ^ (d & 7)) << 4), lv + c * 16);
    }
  };

  for (int pass = 0; pass < 2; pass++) {
    int stile = pass ? 31 - bx : bx;
    int s0 = stile * 64;
    int sq = s0 + wave * 16 + lr;            // this lane's q-row
    bf16x8 qf0 = *(const bf16x8*)&qbase[(size_t)sq * 64 + lg * 8];
    bf16x8 qf1 = *(const bf16x8*)&qbase[(size_t)sq * 64 + 32 + lg * 8];
    f32x4 accv[8] = {};
    float rs = 0.f;
    int nt = stile + 1;

    stage(0, 0);
    __syncthreads();
    for (int it = 0; it < nt; it++) {
      int t0 = it * 64;
      if (it + 1 < nt) stage((it + 1) & 1, t0 + 64);   // overlap with compute
      const unsigned short* lk = (it & 1) ? lk1 : lk0;
      const unsigned short* lv = (it & 1) ? lv1 : lv0;
      bool bnd = (it == nt - 1);
      float rowf = __expf(decay * (float)(sq - t0));
#pragma unroll
      for (int nb = 0; nb < 4; nb++) {
        f32x4 sa = {};
        bf16x8 a0 = *(const bf16x8*)&lk[((nb * 16 + lr) * 64 + lg * 8) ^ swz];
        bf16x8 a1 = *(const bf16x8*)&lk[((nb * 16 + lr) * 64 + 32 + lg * 8) ^ swz];
        __builtin_amdgcn_s_setprio(1);
        sa = mfma16(a0, qf0, sa);            // S^T[t][q]
        sa = mfma16(a1, qf1, sa);
        __builtin_amdgcn_s_setprio(0);
        float pv[4];
#pragma unroll
        for (int r = 0; r < 4; r++) {
          float w = rowf * cf[nb][r];
          if (bnd) {
            int tt = t0 + nb * 16 + lg * 4 + r;
            w = (tt <= sq) ? w : 0.f;
          }
          pv[r] = sa[r] * w;
          rs += pv[r];
        }
        uint2 wv;
        wv.x = cvtpk_bf16(pv[0], pv[1]);
        wv.y = cvtpk_bf16(pv[2], pv[3]);
        *(uint2*)&lpw[lr * LPAD + nb * 16 + lg * 4] = wv;   // P[q][t]
      }
      __builtin_amdgcn_s_setprio(1);
#pragma unroll
      for (int kk = 0; kk < 2; kk++) {
        bf16x8 pa = *(const bf16x8*)&lpw[lr * LPAD + kk * 32 + lg * 8];
#pragma unroll
        for (int nb = 0; nb < 8; nb++) {
          bf16x8 bv = *(const bf16x8*)&lv[((nb * 16 + lr) * 64 + kk * 32 + lg * 8) ^ swz];
          accv[nb] = mfma16(pa, bv, accv[nb]);
        }
      }
      __builtin_amdgcn_s_setprio(0);
      __syncthreads();                       // drains next-tile DMA + frees bufs
    }

    // epilogue: rowsum reduce over lg groups (q-row = lr within wave)
    rs += __shfl_xor(rs, 16);
    rs += __shfl_xor(rs, 32);
    int srb = s0 + wave * 16 + lg * 4;
    const unsigned short* gb2 = &Yg[((size_t)(b * 2048 + srb)) * 6144 + 4096 + h * 128];
    unsigned short* zb = &Z[((size_t)(b * 2048 + srb)) * 2048 + h * 128];
#pragma unroll
    for (int r = 0; r < 4; r++) {
      float rsq = __shfl(rs, lg * 4 + r);
      float sidx = (float)(srb + r);
      float geo = (1.f - __expf(decay * (sidx + 1.f))) * exp2f(5.f + (float)h);
      float invs = rsqrtf(geo);
      float den = fmaxf(fabsf(rsq * invs), 1.f);
      float scl = invs / den;
      float sm = 0.f, sq2 = 0.f;
#pragma unroll
      for (int nb = 0; nb < 8; nb++) {
        float v = accv[nb][r] * scl;
        sm += v; sq2 += v * v;
      }
      sm += __shfl_xor(sm, 1); sm += __shfl_xor(sm, 2);
      sm += __shfl_xor(sm, 4); sm += __shfl_xor(sm, 8);
      sq2 += __shfl_xor(sq2, 1); sq2 += __shfl_xor(sq2, 2);
      sq2 += __shfl_xor(sq2, 4); sq2 += __shfl_xor(sq2, 8);
      float mu = sm * (1.f / 128.f);
      float var = sq2 * (1.f / 128.f) - mu * mu;
      float istd = rsqrtf(var + 1e-5f);
#pragma unroll
      for (int nb = 0; nb < 8; nb++) {
        float v = accv[nb][r] * scl;
        float nrm = (v - mu) * istd;
        float g = bf2f(gb2[(size_t)r * 6144 + nb * 16 + lr]);
        float sg = g / (1.f + __expf(-g));
        zb[(size_t)r * 2048 + nb * 16 + lr] = f2bf(nrm * sg);
      }
    }
  }
}

extern "C" void kernel_launch(void* const* d_in, const int* in_sizes, int n_in,
                              void* d_out, int out_size, void* d_ws, size_t ws_size,
                              hipStream_t stream) {
  const float* x  = (const float*)d_in[0];
  const float* Wq = (const float*)d_in[1];
  const float* bq = (const float*)d_in[2];
  const float* Wk = (const float*)d_in[3];
  const float* bk = (const float*)d_in[4];
  const float* Wv = (const float*)d_in[5];
  const float* bv = (const float*)d_in[6];
  const float* Wg = (const float*)d_in[7];
  const float* bg = (const float*)d_in[8];
  const float* Wo = (const float*)d_in[9];
  const float* bo = (const float*)d_in[10];

  char* ws = (char*)d_ws;
  unsigned short* xbf   = (unsigned short*)(ws);                 // [4096][1024]    8.4 MB
  unsigned short* wcatT = (unsigned short*)(ws + 8388608);       // [6144][1024]   12.6 MB
  unsigned short* woT   = (unsigned short*)(ws + 20971520);      // [1024][2048]    4.2 MB
  unsigned short* Y     = (unsigned short*)(ws + 25165824);      // [4096][6144]   50.3 MB
  unsigned short* qrb   = (unsigned short*)(ws + 75497472);      // [32][2048][64]  8.4 MB
  unsigned short* krb   = (unsigned short*)(ws + 83886080);      // [32][2048][64]  8.4 MB
  unsigned short* vT    = (unsigned short*)(ws + 92274688);      // [32][128][2048] 16.8 MB
  float*          bcat  = (float*)(ws + 109051904);              // [6144]
  unsigned short* Z     = xbf;   // aliases xbf+wcatT (16.8 MB), both dead after GEMM1

  // all weight transposes + x cast + bias concat in ONE launch
  mega_prep_kernel<<<6168, 256, 0, stream>>>(x, Wq, Wk, Wv, Wg, Wo,
                                             bq, bk, bv, bg,
                                             wcatT, woT, xbf, bcat);

  // fused QKVG projection: Y = x @ [Wq|Wk|Wv|Wg] + bias (bf16 out)
  gemm3_kernel<1, 128, 8, 6><<<dim3(48, 32), 256, 0, stream>>>(xbf, wcatT, bcat, Y, 4096, 6144, 1024);

  // prep: RoPE(q,k) + v-transpose in ONE launch
  prep2_kernel<<<9216, 256, 0, stream>>>(Y, qrb, krb, vT);

  // retention + LN + silu gate -> Z (bf16); g read directly from Y
  retention_kernel<<<512, 256, 0, stream>>>(qrb, krb, vT, Y, Z);

  // output projection: out = Z @ Wo + bo (fp32 out), super-tile 4m x 4n
  gemm3_kernel<0, 64, 4, 4><<<dim3(16, 32), 256, 0, stream>>>(Z, woT, bo, d_out, 4096, 1024, 2048);
}

// Round 20
// 161.203 us; speedup vs baseline: 1.3610x; 1.1372x over previous
//
#include <hip/hip_runtime.h>
#include <hip/hip_bf16.h>

typedef __attribute__((ext_vector_type(8))) unsigned short ushort8;
typedef __attribute__((ext_vector_type(4))) float f32x4;
typedef __attribute__((ext_vector_type(8))) __bf16 bf16x8;
typedef unsigned int u32_g __attribute__((address_space(1)));
typedef unsigned int u32_l __attribute__((address_space(3)));

__device__ __forceinline__ float bf2f(unsigned short u) {
  union { unsigned u; float f; } v; v.u = ((unsigned)u) << 16; return v.f;
}
__device__ __forceinline__ unsigned short f2bf(float f) {
  union { float f; unsigned u; } v; v.f = f;
  unsigned r = v.u + 0x7FFFu + ((v.u >> 16) & 1u);
  return (unsigned short)(r >> 16);
}
__device__ __forceinline__ unsigned cvtpk_bf16(float lo, float hi) {
  unsigned r;
  asm("v_cvt_pk_bf16_f32 %0, %1, %2" : "=v"(r) : "v"(lo), "v"(hi));
  return r;
}
__device__ __forceinline__ f32x4 mfma16(bf16x8 a, bf16x8 b, f32x4 c) {
  return __builtin_amdgcn_mfma_f32_16x16x32_bf16(a, b, c, 0, 0, 0);
}
__device__ __forceinline__ void gload16(const void* g, void* l) {
  __builtin_amdgcn_global_load_lds((const u32_g*)g, (u32_l*)l, 16, 0, 0);
}

// ---------------- mega prep: 5 weight transposes + cast_x + biascat in one launch
__device__ __forceinline__ void tc_body(
    const float* __restrict__ W, unsigned short* __restrict__ WT,
    int K, int N, int ldwt, int row_off, int bx, int by, int tid,
    unsigned short* t)
{
  int n0 = bx * 64, k0 = by * 64;
#pragma unroll
  for (int i = 0; i < 4; i++) {
    int c = tid + 256 * i;
    int r = c >> 4, q = c & 15;
    float4 v = *(const float4*)&W[(size_t)(k0 + r) * N + n0 + q * 4];
    t[(q * 4 + 0) * 80 + r] = f2bf(v.x);
    t[(q * 4 + 1) * 80 + r] = f2bf(v.y);
    t[(q * 4 + 2) * 80 + r] = f2bf(v.z);
    t[(q * 4 + 3) * 80 + r] = f2bf(v.w);
  }
  __syncthreads();
#pragma unroll
  for (int i = 0; i < 2; i++) {
    int c = tid + 256 * i;
    int n = c >> 3, p = c & 7;
    *(ushort8*)&WT[(size_t)(row_off + n0 + n) * ldwt + k0 + p * 8] =
        *(const ushort8*)&t[n * 80 + p * 8];
  }
}

__global__ __launch_bounds__(256) void mega_prep_kernel(
    const float* __restrict__ x,
    const float* __restrict__ Wq, const float* __restrict__ Wk,
    const float* __restrict__ Wv, const float* __restrict__ Wg,
    const float* __restrict__ Wo,
    const float* __restrict__ bq, const float* __restrict__ bk,
    const float* __restrict__ bv, const float* __restrict__ bg,
    unsigned short* __restrict__ wcatT, unsigned short* __restrict__ woT,
    unsigned short* __restrict__ xbf, float* __restrict__ bcat)
{
  __shared__ unsigned short t[64 * 80];
  int bid = blockIdx.x, tid = threadIdx.x;
  if (bid < 256) {
    tc_body(Wq, wcatT, 1024, 1024, 1024, 0, bid & 15, bid >> 4, tid, t);
  } else if (bid < 512) {
    int l = bid - 256;
    tc_body(Wk, wcatT, 1024, 1024, 1024, 1024, l & 15, l >> 4, tid, t);
  } else if (bid < 1024) {
    int l = bid - 512;
    tc_body(Wv, wcatT, 1024, 2048, 1024, 2048, l & 31, l >> 5, tid, t);
  } else if (bid < 1536) {
    int l = bid - 1024;
    tc_body(Wg, wcatT, 1024, 2048, 1024, 4096, l & 31, l >> 5, tid, t);
  } else if (bid < 2048) {
    int l = bid - 1536;
    tc_body(Wo, woT, 2048, 1024, 2048, 0, l & 15, l >> 4, tid, t);
  } else if (bid < 6144) {
    size_t i = (size_t)((bid - 2048) * 256 + tid) * 4;
    float4 v = *(const float4*)&x[i];
    unsigned r0 = (unsigned)f2bf(v.x) | ((unsigned)f2bf(v.y) << 16);
    unsigned r1 = (unsigned)f2bf(v.z) | ((unsigned)f2bf(v.w) << 16);
    uint2 o; o.x = r0; o.y = r1;
    *(uint2*)&xbf[i] = o;
  } else {
    int i = (bid - 6144) * 256 + tid;   // 6144
    float v;
    if (i < 1024) v = bq[i];
    else if (i < 2048) v = bk[i - 1024];
    else if (i < 4096) v = bv[i - 2048];
    else v = bg[i - 4096];
    bcat[i] = v;
  }
}

// ---------------- GEMM3: 128xBN tile, BK=32, 3-buffer counted-vmcnt pipeline,
// 2D super-tile XCD mapping. OUT_MODE 0: fp32 Cout. OUT_MODE 1 (QKVG split):
// epilogue routes by block-uniform section: q/k -> in-register RoPE -> qrb/krb,
// v -> transposed write to vT, g -> Y. Eliminates the prep2 kernel round-trip.
template<int OUT_MODE, int BN, int SM, int SN>
__global__ __launch_bounds__(256, 3) void gemm3_kernel(
    const unsigned short* __restrict__ A, const unsigned short* __restrict__ BT,
    const float* __restrict__ bias, void* __restrict__ Cout,
    unsigned short* __restrict__ qout, unsigned short* __restrict__ kout,
    unsigned short* __restrict__ vout, unsigned short* __restrict__ gout,
    int M, int N, int K)
{
  constexpr int BUFS = (128 + BN) * 32;
  constexpr int ACH  = 512;
  constexpr int LPS  = (128 + BN) / 64;
  constexpr int STB  = SM * SN;
  __shared__ __attribute__((aligned(16))) unsigned short lds[3 * BUFS];
  int tid = threadIdx.x, wave = tid >> 6, lane = tid & 63;
  int lr = lane & 15, lg = lane >> 4;
  int gx = gridDim.x;
  int lin = blockIdx.x + gx * blockIdx.y;
  int cpx = (gx * gridDim.y) >> 3;
  int xcd = lin & 7, s = lin >> 3;
  int spx = cpx / STB;
  int sup = xcd * spx + s / STB;
  int nSupN = gx / SN;
  int stm = sup / nSupN, stn = sup % nSupN;
  int idx = s % STB;
  int m0 = (stm * SM + idx / SN) * 128;
  int n0 = (stn * SN + idx % SN) * BN;
  int wr = (wave >> 1) * 64, wc = (wave & 1) * (BN / 2);
  constexpr int NR = BN / 32;

  const unsigned short* gsrc[LPS];
#pragma unroll
  for (int i = 0; i < LPS; i++) {
    int c = tid + i * 256;
    if (c < ACH) {
      int r = c >> 2, j = c & 3;
      gsrc[i] = A + (size_t)(m0 + r) * K + ((j ^ ((r >> 1) & 3)) << 3);
    } else {
      int c2 = c - ACH, r = c2 >> 2, j = c2 & 3;
      gsrc[i] = BT + (size_t)(n0 + r) * K + ((j ^ ((r >> 1) & 3)) << 3);
    }
  }

  auto stage = [&](int buf, int kt) {
    char* lb = (char*)(lds + buf * BUFS);
#pragma unroll
    for (int i = 0; i < LPS; i++)
      gload16(gsrc[i] + kt * 32, lb + (tid + i * 256) * 16);
  };

  f32x4 acc[4][NR] = {};
  int nk = K >> 5;
  stage(0, 0);
  stage(1, 1);
  int cb = 0;
  for (int it = 0; it < nk; it++) {
    if (it + 1 < nk) {
      if constexpr (LPS == 4) asm volatile("s_waitcnt vmcnt(4)" ::: "memory");
      else                    asm volatile("s_waitcnt vmcnt(3)" ::: "memory");
    } else {
      asm volatile("s_waitcnt vmcnt(0)" ::: "memory");
    }
    __builtin_amdgcn_sched_barrier(0);
    __builtin_amdgcn_s_barrier();
    __builtin_amdgcn_sched_barrier(0);
    if (it + 2 < nk) {
      int sb = cb + 2; if (sb >= 3) sb -= 3;
      stage(sb, it + 2);
    }
    const unsigned short* as = lds + cb * BUFS;
    const unsigned short* bs = as + 128 * 32;
    int csw = (lg ^ ((lr >> 1) & 3)) << 3;
    bf16x8 af[4], bfr[NR];
#pragma unroll
    for (int m = 0; m < 4; m++)
      af[m] = *(const bf16x8*)&as[(wr + m * 16 + lr) * 32 + csw];
#pragma unroll
    for (int n = 0; n < NR; n++)
      bfr[n] = *(const bf16x8*)&bs[(wc + n * 16 + lr) * 32 + csw];
    __builtin_amdgcn_s_setprio(1);
#pragma unroll
    for (int m = 0; m < 4; m++)
#pragma unroll
      for (int n = 0; n < NR; n++)
        acc[m][n] = mfma16(af[m], bfr[n], acc[m][n]);
    __builtin_amdgcn_s_setprio(0);
    cb++; if (cb == 3) cb = 0;
  }

  if constexpr (OUT_MODE == 0) {
#pragma unroll
    for (int m = 0; m < 4; m++) {
#pragma unroll
      for (int n = 0; n < NR; n++) {
        int col = n0 + wc + n * 16 + lr;
        float bv = bias ? bias[col] : 0.f;
#pragma unroll
        for (int r = 0; r < 4; r++) {
          int row = m0 + wr + m * 16 + lg * 4 + r;
          ((float*)Cout)[(size_t)row * N + col] = acc[m][n][r] + bv;
        }
      }
    }
  } else {
    int b = m0 >> 11;                           // batch (block rows within one b)
    if (n0 < 2048) {
      // q or k: in-register RoPE (pair partner one lane over), k scaled 0.125
      const bool isk = (n0 >= 1024);
      unsigned short* dst = isk ? kout : qout;
      float kscale = isk ? 0.125f : 1.0f;
#pragma unroll
      for (int m = 0; m < 4; m++) {
#pragma unroll
        for (int n = 0; n < NR; n++) {
          int col = n0 + wc + n * 16 + lr;
          int cc = col & 63, hh = (col & 1023) >> 6;
          float ang = __expf(-0.29710774f * (float)(cc >> 1));
          float bv = bias[col];
          int odd = col & 1;
#pragma unroll
          for (int r = 0; r < 4; r++) {
            int row = m0 + wr + m * 16 + lg * 4 + r;
            float v = acc[m][n][r] + bv;
            float p = __shfl_xor(v, 1);
            float sn, cs;
            __sincosf((float)(row & 2047) * ang, &sn, &cs);
            float out = odd ? (v * cs + p * sn) : (v * cs - p * sn);
            dst[((size_t)(b * 16 + hh) * 2048 + (row & 2047)) * 64 + cc] =
                f2bf(out * kscale);
          }
        }
      }
    } else if (n0 < 4096) {
      // v: transposed write to vT[bh*128+d][s], 4 consecutive s per store
#pragma unroll
      for (int m = 0; m < 4; m++) {
#pragma unroll
        for (int n = 0; n < NR; n++) {
          int col = n0 + wc + n * 16 + lr;
          int vcol = col - 2048, hh = vcol >> 7, d = vcol & 127;
          float bv = bias[col];
          int s0 = (m0 + wr + m * 16 + lg * 4) & 2047;
          uint2 wv;
          wv.x = (unsigned)f2bf(acc[m][n][0] + bv) | ((unsigned)f2bf(acc[m][n][1] + bv) << 16);
          wv.y = (unsigned)f2bf(acc[m][n][2] + bv) | ((unsigned)f2bf(acc[m][n][3] + bv) << 16);
          *(uint2*)&vout[((size_t)(b * 16 + hh) * 128 + d) * 2048 + s0] = wv;
        }
      }
    } else {
      // g: write Y (retention reads g from Y)
#pragma unroll
      for (int m = 0; m < 4; m++) {
#pragma unroll
        for (int n = 0; n < NR; n++) {
          int col = n0 + wc + n * 16 + lr;
          float bv = bias[col];
#pragma unroll
          for (int r = 0; r < 4; r++) {
            int row = m0 + wr + m * 16 + lg * 4 + r;
            gout[(size_t)row * 6144 + col] = f2bf(acc[m][n][r] + bv);
          }
        }
      }
    }
  }
}

// ---------------- retention: swapped-QK, XCD-local bh, DMA double-buffered K/V
// (R3 balanced-pair structure; P packing via v_cvt_pk_bf16_f32; T5 setprio)
#define LPAD 72
__global__ __launch_bounds__(256, 2) void retention_kernel(
    const unsigned short* __restrict__ qr, const unsigned short* __restrict__ kr,
    const unsigned short* __restrict__ vT, const unsigned short* __restrict__ Yg,
    unsigned short* __restrict__ Z)
{
  // shorts: kA[4096] kB[4096] vA[8192] vB[8192] lp[4*16*72]
  __shared__ __attribute__((aligned(16))) unsigned short lds[24576 + 4 * 16 * LPAD];
  unsigned short* const lk0 = lds;
  unsigned short* const lk1 = lds + 4096;
  unsigned short* const lv0 = lds + 8192;
  unsigned short* const lv1 = lds + 16384;
  unsigned short* const lp  = lds + 24576;

  int lin = blockIdx.x;            // 0..511
  int xcd = lin & 7, slot = lin >> 3;
  int bh = xcd + 8 * (slot >> 4);
  int bx = slot & 15;
  int b = bh >> 4, h = bh & 15;
  float decay = __logf(1.f - exp2f(-5.f - (float)h));
  int tid = threadIdx.x, wave = tid >> 6, lane = tid & 63;
  int lr = lane & 15, lg = lane >> 4;
  const unsigned short* qbase = &qr[(size_t)bh * 2048 * 64];
  const unsigned short* kbase = &kr[(size_t)bh * 2048 * 64];
  const unsigned short* vbase = &vT[(size_t)bh * 128 * 2048];
  unsigned short* lpw = &lp[wave * 16 * LPAD];
  int swz = (lr & 7) << 3;

  float cf[4][4];
#pragma unroll
  for (int nb = 0; nb < 4; nb++)
#pragma unroll
    for (int r = 0; r < 4; r++)
      cf[nb][r] = __expf(-decay * (float)(nb * 16 + lg * 4 + r));

  auto stage = [&](int bufi, int t0) {
    const char* kg = (const char*)(kbase + (size_t)t0 * 64);
    const char* vg = (const char*)vbase + (size_t)t0 * 2;
    char* lk = (char*)(bufi ? lk1 : lk0);
    char* lv = (char*)(bufi ? lv1 : lv0);
#pragma unroll
    for (int i = 0; i < 2; i++) {
      int c = tid + i * 256;
      int r = c >> 3, j = c & 7;
      gload16(kg + r * 128 + ((j ^ (r & 7)) << 4), lk + c * 16);
    }
#pragma unroll
    for (int i = 0; i < 4; i++) {
      int c = tid + i * 256;
      int d = c >> 3, j = c & 7;
      gload16(vg + (size_t)d * 4096 + ((j ^ (d & 7)) << 4), lv + c * 16);
    }
  };

  for (int pass = 0; pass < 2; pass++) {
    int stile = pass ? 31 - bx : bx;
    int s0 = stile * 64;
    int sq = s0 + wave * 16 + lr;
    bf16x8 qf0 = *(const bf16x8*)&qbase[(size_t)sq * 64 + lg * 8];
    bf16x8 qf1 = *(const bf16x8*)&qbase[(size_t)sq * 64 + 32 + lg * 8];
    f32x4 accv[8] = {};
    float rs = 0.f;
    int nt = stile + 1;

    stage(0, 0);
    __syncthreads();
    for (int it = 0; it < nt; it++) {
      int t0 = it * 64;
      if (it + 1 < nt) stage((it + 1) & 1, t0 + 64);
      const unsigned short* lk = (it & 1) ? lk1 : lk0;
      const unsigned short* lv = (it & 1) ? lv1 : lv0;
      bool bnd = (it == nt - 1);
      float rowf = __expf(decay * (float)(sq - t0));
#pragma unroll
      for (int nb = 0; nb < 4; nb++) {
        f32x4 sa = {};
        bf16x8 a0 = *(const bf16x8*)&lk[((nb * 16 + lr) * 64 + lg * 8) ^ swz];
        bf16x8 a1 = *(const bf16x8*)&lk[((nb * 16 + lr) * 64 + 32 + lg * 8) ^ swz];
        __builtin_amdgcn_s_setprio(1);
        sa = mfma16(a0, qf0, sa);
        sa = mfma16(a1, qf1, sa);
        __builtin_amdgcn_s_setprio(0);
        float pv[4];
#pragma unroll
        for (int r = 0; r < 4; r++) {
          float w = rowf * cf[nb][r];
          if (bnd) {
            int tt = t0 + nb * 16 + lg * 4 + r;
            w = (tt <= sq) ? w : 0.f;
          }
          pv[r] = sa[r] * w;
          rs += pv[r];
        }
        uint2 wv;
        wv.x = cvtpk_bf16(pv[0], pv[1]);
        wv.y = cvtpk_bf16(pv[2], pv[3]);
        *(uint2*)&lpw[lr * LPAD + nb * 16 + lg * 4] = wv;
      }
      __builtin_amdgcn_s_setprio(1);
#pragma unroll
      for (int kk = 0; kk < 2; kk++) {
        bf16x8 pa = *(const bf16x8*)&lpw[lr * LPAD + kk * 32 + lg * 8];
#pragma unroll
        for (int nb = 0; nb < 8; nb++) {
          bf16x8 bv = *(const bf16x8*)&lv[((nb * 16 + lr) * 64 + kk * 32 + lg * 8) ^ swz];
          accv[nb] = mfma16(pa, bv, accv[nb]);
        }
      }
      __builtin_amdgcn_s_setprio(0);
      __syncthreads();
    }

    rs += __shfl_xor(rs, 16);
    rs += __shfl_xor(rs, 32);
    int srb = s0 + wave * 16 + lg * 4;
    const unsigned short* gb2 = &Yg[((size_t)(b * 2048 + srb)) * 6144 + 4096 + h * 128];
    unsigned short* zb = &Z[((size_t)(b * 2048 + srb)) * 2048 + h * 128];
#pragma unroll
    for (int r = 0; r < 4; r++) {
      float rsq = __shfl(rs, lg * 4 + r);
      float sidx = (float)(srb + r);
      float geo = (1.f - __expf(decay * (sidx + 1.f))) * exp2f(5.f + (float)h);
      float invs = rsqrtf(geo);
      float den = fmaxf(fabsf(rsq * invs), 1.f);
      float scl = invs / den;
      float sm = 0.f, sq2 = 0.f;
#pragma unroll
      for (int nb = 0; nb < 8; nb++) {
        float v = accv[nb][r] * scl;
        sm += v; sq2 += v * v;
      }
      sm += __shfl_xor(sm, 1); sm += __shfl_xor(sm, 2);
      sm += __shfl_xor(sm, 4); sm += __shfl_xor(sm, 8);
      sq2 += __shfl_xor(sq2, 1); sq2 += __shfl_xor(sq2, 2);
      sq2 += __shfl_xor(sq2, 4); sq2 += __shfl_xor(sq2, 8);
      float mu = sm * (1.f / 128.f);
      float var = sq2 * (1.f / 128.f) - mu * mu;
      float istd = rsqrtf(var + 1e-5f);
#pragma unroll
      for (int nb = 0; nb < 8; nb++) {
        float v = accv[nb][r] * scl;
        float nrm = (v - mu) * istd;
        float g = bf2f(gb2[(size_t)r * 6144 + nb * 16 + lr]);
        float sg = g / (1.f + __expf(-g));
        zb[(size_t)r * 2048 + nb * 16 + lr] = f2bf(nrm * sg);
      }
    }
  }
}

extern "C" void kernel_launch(void* const* d_in, const int* in_sizes, int n_in,
                              void* d_out, int out_size, void* d_ws, size_t ws_size,
                              hipStream_t stream) {
  const float* x  = (const float*)d_in[0];
  const float* Wq = (const float*)d_in[1];
  const float* bq = (const float*)d_in[2];
  const float* Wk = (const float*)d_in[3];
  const float* bk = (const float*)d_in[4];
  const float* Wv = (const float*)d_in[5];
  const float* bv = (const float*)d_in[6];
  const float* Wg = (const float*)d_in[7];
  const float* bg = (const float*)d_in[8];
  const float* Wo = (const float*)d_in[9];
  const float* bo = (const float*)d_in[10];

  char* ws = (char*)d_ws;
  unsigned short* xbf   = (unsigned short*)(ws);                 // [4096][1024]    8.4 MB
  unsigned short* wcatT = (unsigned short*)(ws + 8388608);       // [6144][1024]   12.6 MB
  unsigned short* woT   = (unsigned short*)(ws + 20971520);      // [1024][2048]    4.2 MB
  unsigned short* Y     = (unsigned short*)(ws + 25165824);      // [4096][6144]   50.3 MB (g only)
  unsigned short* qrb   = (unsigned short*)(ws + 75497472);      // [32][2048][64]  8.4 MB
  unsigned short* krb   = (unsigned short*)(ws + 83886080);      // [32][2048][64]  8.4 MB
  unsigned short* vT    = (unsigned short*)(ws + 92274688);      // [32][128][2048] 16.8 MB
  float*          bcat  = (float*)(ws + 109051904);              // [6144]
  unsigned short* Z     = xbf;   // aliases xbf+wcatT, both dead after GEMM1

  // all weight transposes + x cast + bias concat in ONE launch
  mega_prep_kernel<<<6168, 256, 0, stream>>>(x, Wq, Wk, Wv, Wg, Wo,
                                             bq, bk, bv, bg,
                                             wcatT, woT, xbf, bcat);

  // fused QKVG projection + RoPE + v-transpose + g-store (prep2 eliminated)
  gemm3_kernel<1, 128, 4, 4><<<dim3(48, 32), 256, 0, stream>>>(
      xbf, wcatT, bcat, nullptr, qrb, krb, vT, Y, 4096, 6144, 1024);

  // retention + LN + silu gate -> Z (bf16); g read directly from Y
  retention_kernel<<<512, 256, 0, stream>>>(qrb, krb, vT, Y, Z);

  // output projection: out = Z @ Wo + bo (fp32 out), super-tile 4m x 4n
  gemm3_kernel<0, 64, 4, 4><<<dim3(16, 32), 256, 0, stream>>>(
      Z, woT, bo, d_out, nullptr, nullptr, nullptr, nullptr, 4096, 1024, 2048);
}